// Round 1
// baseline (369.645 us; speedup 1.0000x reference)
//
#include <hip/hip_runtime.h>

#define BATCH 64
#define NH 32
#define NKV 8
#define GQA 4        // NH / NKV
#define HD 128
#define SEQ 4096
#define BS 256
#define BPS 16
#define QK_SCALE 0.08838834764831845f

__device__ __forceinline__ long long load_idx(const void* p, int i, bool is64) {
    return is64 ? ((const long long*)p)[i] : (long long)((const int*)p)[i];
}

__global__ __launch_bounds__(256, 2) void pa_decode(
    const float* __restrict__ q,
    const float* __restrict__ knew,
    const float* __restrict__ vnew,
    const float* __restrict__ kc,
    const float* __restrict__ vc,
    const void* __restrict__ slot_mapping,
    const void* __restrict__ block_tables,
    const void* __restrict__ context_lens,
    float* __restrict__ out)
{
    const int g    = blockIdx.x;   // kv head
    const int b    = blockIdx.y;   // batch
    const int tid  = threadIdx.x;
    const int wave = tid >> 6;
    const int lane = tid & 63;
    const int grp  = lane >> 3;    // key slot within 8-key tile
    const int l8   = lane & 7;     // lane within key group

    // int64 (reference dtype) vs int32 detection: identity block table
    // int64 little-endian view as int32: [0,0,1,0,...] -> [1]==0
    const bool is64 = (((const int*)block_tables)[1] == 0);
    const long long ctx    = load_idx(context_lens, b, is64);
    const long long target = load_idx(slot_mapping, b, is64);

    __shared__ int bt_s[BPS];
    __shared__ __align__(16) float acc_lds[4][GQA][HD];
    __shared__ float m_lds[4][GQA];
    __shared__ float l_lds[4][GQA];

    if (tid < BPS) bt_s[tid] = (int)load_idx(block_tables, b * BPS + tid, is64);
    __syncthreads();

    // q fragments, pre-scaled: lane covers dims (i*8+l8)*4 .. +3, i=0..3
    float4 qs[GQA][4];
#pragma unroll
    for (int h = 0; h < GQA; ++h) {
#pragma unroll
        for (int i = 0; i < 4; ++i) {
            float4 t = *(const float4*)(q + (size_t)b * NH * HD + (g * GQA + h) * HD + (i * 8 + l8) * 4);
            qs[h][i] = make_float4(t.x * QK_SCALE, t.y * QK_SCALE, t.z * QK_SCALE, t.w * QK_SCALE);
        }
    }

    float4 acc[GQA][4];
    float m_run[GQA], l_run[GQA];
#pragma unroll
    for (int h = 0; h < GQA; ++h) {
        m_run[h] = -1e30f;
        l_run[h] = 0.f;
#pragma unroll
        for (int i = 0; i < 4; ++i) acc[h][i] = make_float4(0.f, 0.f, 0.f, 0.f);
    }

    const float* knew_b = knew + ((size_t)b * NKV + g) * HD;
    const float* vnew_b = vnew + ((size_t)b * NKV + g) * HD;

    const int s0 = wave * (SEQ / 4);

#pragma unroll 2
    for (int t = 0; t < (SEQ / 4) / 8; ++t) {
        const int s = s0 + t * 8 + grp;
        const int blk = bt_s[s >> 8];
        const long long slot = (long long)blk * BS + (s & (BS - 1));
        const bool isnew = (slot == target);
        const float* kb = isnew ? knew_b : (kc + ((size_t)slot * NKV + g) * HD);
        const float* vb = isnew ? vnew_b : (vc + ((size_t)slot * NKV + g) * HD);

        float4 kv[4], vv[4];
#pragma unroll
        for (int i = 0; i < 4; ++i) kv[i] = *(const float4*)(kb + (i * 8 + l8) * 4);
#pragma unroll
        for (int i = 0; i < 4; ++i) vv[i] = *(const float4*)(vb + (i * 8 + l8) * 4);

        // per-lane partial dot for 4 heads
        float sc[GQA];
#pragma unroll
        for (int h = 0; h < GQA; ++h) {
            float a = 0.f;
#pragma unroll
            for (int i = 0; i < 4; ++i) {
                a += qs[h][i].x * kv[i].x;
                a += qs[h][i].y * kv[i].y;
                a += qs[h][i].z * kv[i].z;
                a += qs[h][i].w * kv[i].w;
            }
            sc[h] = a;
        }
        // reduce within 8-lane key group (bits 0..2)
#pragma unroll
        for (int h = 0; h < GQA; ++h) {
            sc[h] += __shfl_xor(sc[h], 1);
            sc[h] += __shfl_xor(sc[h], 2);
            sc[h] += __shfl_xor(sc[h], 4);
        }

        const bool valid = (s < ctx);
#pragma unroll
        for (int h = 0; h < GQA; ++h) if (!valid) sc[h] = -1e30f;

        // tile max across the 8 key groups (bits 3..5) -> wave-uniform
        float mt[GQA];
#pragma unroll
        for (int h = 0; h < GQA; ++h) {
            float mv = sc[h];
            mv = fmaxf(mv, __shfl_xor(mv, 8));
            mv = fmaxf(mv, __shfl_xor(mv, 16));
            mv = fmaxf(mv, __shfl_xor(mv, 32));
            mt[h] = mv;
        }

        // online softmax state update (wave-uniform branch, rare)
#pragma unroll
        for (int h = 0; h < GQA; ++h) {
            if (mt[h] > m_run[h]) {
                const float scl = __expf(m_run[h] - mt[h]);
                m_run[h] = mt[h];
                l_run[h] *= scl;
#pragma unroll
                for (int i = 0; i < 4; ++i) {
                    acc[h][i].x *= scl; acc[h][i].y *= scl;
                    acc[h][i].z *= scl; acc[h][i].w *= scl;
                }
            }
        }

        float p[GQA];
#pragma unroll
        for (int h = 0; h < GQA; ++h) {
            p[h] = valid ? __expf(sc[h] - m_run[h]) : 0.f;
            float ps = p[h];
            ps += __shfl_xor(ps, 8);
            ps += __shfl_xor(ps, 16);
            ps += __shfl_xor(ps, 32);
            l_run[h] += ps;
        }

        // V accumulate: lane owns 16 dims x 4 heads
#pragma unroll
        for (int h = 0; h < GQA; ++h) {
#pragma unroll
            for (int i = 0; i < 4; ++i) {
                acc[h][i].x += p[h] * vv[i].x;
                acc[h][i].y += p[h] * vv[i].y;
                acc[h][i].z += p[h] * vv[i].z;
                acc[h][i].w += p[h] * vv[i].w;
            }
        }
    }

    // sum partial accumulators across the 8 key groups (bits 3..5)
#pragma unroll
    for (int h = 0; h < GQA; ++h) {
#pragma unroll
        for (int i = 0; i < 4; ++i) {
            acc[h][i].x += __shfl_xor(acc[h][i].x, 8);
            acc[h][i].x += __shfl_xor(acc[h][i].x, 16);
            acc[h][i].x += __shfl_xor(acc[h][i].x, 32);
            acc[h][i].y += __shfl_xor(acc[h][i].y, 8);
            acc[h][i].y += __shfl_xor(acc[h][i].y, 16);
            acc[h][i].y += __shfl_xor(acc[h][i].y, 32);
            acc[h][i].z += __shfl_xor(acc[h][i].z, 8);
            acc[h][i].z += __shfl_xor(acc[h][i].z, 16);
            acc[h][i].z += __shfl_xor(acc[h][i].z, 32);
            acc[h][i].w += __shfl_xor(acc[h][i].w, 8);
            acc[h][i].w += __shfl_xor(acc[h][i].w, 16);
            acc[h][i].w += __shfl_xor(acc[h][i].w, 32);
        }
    }

    if (grp == 0) {
#pragma unroll
        for (int h = 0; h < GQA; ++h) {
#pragma unroll
            for (int i = 0; i < 4; ++i)
                *(float4*)&acc_lds[wave][h][(i * 8 + l8) * 4] = acc[h][i];
            if (l8 == 0) { m_lds[wave][h] = m_run[h]; l_lds[wave][h] = l_run[h]; }
        }
    }
    __syncthreads();

    // combine the 4 waves' partial softmax states; 512 outputs, 2 per thread
    for (int o = tid; o < GQA * HD; o += 256) {
        const int h = o >> 7;
        const int d = o & (HD - 1);
        float mm = -1e30f;
#pragma unroll
        for (int w = 0; w < 4; ++w) mm = fmaxf(mm, m_lds[w][h]);
        float num = 0.f, den = 0.f;
#pragma unroll
        for (int w = 0; w < 4; ++w) {
            const float wt = __expf(m_lds[w][h] - mm);
            num += wt * acc_lds[w][h][d];
            den += wt * l_lds[w][h];
        }
        out[(size_t)b * NH * HD + (g * GQA + h) * HD + d] = num / den;
    }
}

extern "C" void kernel_launch(void* const* d_in, const int* in_sizes, int n_in,
                              void* d_out, int out_size, void* d_ws, size_t ws_size,
                              hipStream_t stream) {
    const float* q    = (const float*)d_in[0];
    const float* k    = (const float*)d_in[1];
    const float* v    = (const float*)d_in[2];
    const float* kc   = (const float*)d_in[3];
    const float* vc   = (const float*)d_in[4];
    const void*  slot = d_in[5];
    const void*  bt   = d_in[6];
    const void*  cl   = d_in[7];
    float* out = (float*)d_out;

    dim3 grid(NKV, BATCH);
    pa_decode<<<grid, 256, 0, stream>>>(q, k, v, kc, vc, slot, bt, cl, out);
}

// Round 2
// 313.633 us; speedup vs baseline: 1.1786x; 1.1786x over previous
//
#include <hip/hip_runtime.h>

#define BATCH 64
#define NH 32
#define NKV 8
#define GQA 4        // NH / NKV
#define HD 128
#define SEQ 4096
#define BS 256
#define BPS 16
#define QK_SCALE 0.08838834764831845f
#define DEFER_THR 8.0f

typedef float f32x4 __attribute__((ext_vector_type(4)));

__device__ __forceinline__ long long load_idx(const void* p, int i, bool is64) {
    return is64 ? ((const long long*)p)[i] : (long long)((const int*)p)[i];
}

__device__ __forceinline__ float4 ldnt(const float* p) {
    f32x4 v = __builtin_nontemporal_load(reinterpret_cast<const f32x4*>(p));
    return make_float4(v.x, v.y, v.z, v.w);
}

__global__ __launch_bounds__(256, 2) void pa_decode(
    const float* __restrict__ q,
    const float* __restrict__ knew,
    const float* __restrict__ vnew,
    const float* __restrict__ kc,
    const float* __restrict__ vc,
    const void* __restrict__ slot_mapping,
    const void* __restrict__ block_tables,
    const void* __restrict__ context_lens,
    float* __restrict__ out)
{
    const int g    = blockIdx.x;   // kv head
    const int b    = blockIdx.y;   // batch
    const int tid  = threadIdx.x;
    const int wave = tid >> 6;
    const int lane = tid & 63;
    const int grp  = lane >> 3;    // key slot within 8-key tile
    const int l8   = lane & 7;     // lane within key group

    // int64 (reference dtype) vs int32 detection via identity block table
    const bool is64 = (((const int*)block_tables)[1] == 0);
    const long long ctx    = load_idx(context_lens, b, is64);
    const long long target = load_idx(slot_mapping, b, is64);

    __shared__ int bt_s[BPS];
    __shared__ __align__(16) float acc_lds[4][GQA][HD];
    __shared__ float m_lds[4][GQA];
    __shared__ float l_lds[4][GQA];

    if (tid < BPS) bt_s[tid] = (int)load_idx(block_tables, b * BPS + tid, is64);
    __syncthreads();

    // q fragments, pre-scaled: lane covers dims (i*8+l8)*4 .. +3, i=0..3
    float4 qs[GQA][4];
#pragma unroll
    for (int h = 0; h < GQA; ++h) {
#pragma unroll
        for (int i = 0; i < 4; ++i) {
            float4 t = *(const float4*)(q + (size_t)b * NH * HD + (g * GQA + h) * HD + (i * 8 + l8) * 4);
            qs[h][i] = make_float4(t.x * QK_SCALE, t.y * QK_SCALE, t.z * QK_SCALE, t.w * QK_SCALE);
        }
    }

    float4 acc[GQA][4];
    float m_run[GQA], l_run[GQA];
#pragma unroll
    for (int h = 0; h < GQA; ++h) {
        m_run[h] = -1e30f;
        l_run[h] = 0.f;
#pragma unroll
        for (int i = 0; i < 4; ++i) acc[h][i] = make_float4(0.f, 0.f, 0.f, 0.f);
    }

    const float* knew_b = knew + ((size_t)b * NKV + g) * HD;
    const float* vnew_b = vnew + ((size_t)b * NKV + g) * HD;

    const int s0 = wave * (SEQ / 4);

    // full tiles (all 8 keys valid) vs one masked boundary tile
    const long long cr = ctx - (long long)s0;
    const int rem = (int)(cr < 0 ? 0 : (cr > 1024 ? 1024 : cr));
    const int nt  = rem >> 3;
    const bool tail = (rem & 7) != 0;

    auto mkaddr = [&](int t, const float*& kb, const float*& vb) {
        const int s = s0 + t * 8 + grp;
        const int blk = bt_s[s >> 8];
        const long long slot = (long long)blk * BS + (s & (BS - 1));
        const bool isnew = (slot == target);
        kb = isnew ? knew_b : (kc + ((size_t)slot * NKV + g) * HD);
        vb = isnew ? vnew_b : (vc + ((size_t)slot * NKV + g) * HD);
    };

    auto compute = [&](const float4 (&kvt)[4], const float4 (&vvt)[4], int t, bool masked) {
        float sc[GQA];
#pragma unroll
        for (int h = 0; h < GQA; ++h) {
            float a = 0.f;
#pragma unroll
            for (int i = 0; i < 4; ++i) {
                a += qs[h][i].x * kvt[i].x;
                a += qs[h][i].y * kvt[i].y;
                a += qs[h][i].z * kvt[i].z;
                a += qs[h][i].w * kvt[i].w;
            }
            // reduce within 8-lane key group (bits 0..2) -> group-uniform
            a += __shfl_xor(a, 1);
            a += __shfl_xor(a, 2);
            a += __shfl_xor(a, 4);
            sc[h] = a;
        }
        if (masked) {
            const int s = s0 + t * 8 + grp;
            if ((long long)s >= ctx) {
#pragma unroll
                for (int h = 0; h < GQA; ++h) sc[h] = -1e30f;
            }
        }
#pragma unroll
        for (int h = 0; h < GQA; ++h) {
            // defer-max: exact rescale only when max actually grows past slack
            if (__any(sc[h] > m_run[h] + DEFER_THR)) {
                float mv = sc[h];
                mv = fmaxf(mv, __shfl_xor(mv, 8));
                mv = fmaxf(mv, __shfl_xor(mv, 16));
                mv = fmaxf(mv, __shfl_xor(mv, 32));
                const float newm = fmaxf(m_run[h], mv);
                const float scl = __expf(m_run[h] - newm);
                m_run[h] = newm;
                l_run[h] *= scl;
#pragma unroll
                for (int i = 0; i < 4; ++i) {
                    acc[h][i].x *= scl; acc[h][i].y *= scl;
                    acc[h][i].z *= scl; acc[h][i].w *= scl;
                }
            }
            const float p = __expf(sc[h] - m_run[h]);  // bounded by e^DEFER_THR
            l_run[h] += p;                              // per-group partial; reduced at end
#pragma unroll
            for (int i = 0; i < 4; ++i) {
                acc[h][i].x += p * vvt[i].x;
                acc[h][i].y += p * vvt[i].y;
                acc[h][i].z += p * vvt[i].z;
                acc[h][i].w += p * vvt[i].w;
            }
        }
    };

    float4 kv[4], vv[4], kv2[4], vv2[4];

    if (nt > 0) {
        const float *kb, *vb;
        mkaddr(0, kb, vb);
#pragma unroll
        for (int i = 0; i < 4; ++i) kv[i] = ldnt(kb + (i * 8 + l8) * 4);
#pragma unroll
        for (int i = 0; i < 4; ++i) vv[i] = ldnt(vb + (i * 8 + l8) * 4);
    }

#pragma unroll 2
    for (int t = 0; t < nt; ++t) {
        if (t + 1 < nt) {
            const float *kb, *vb;
            mkaddr(t + 1, kb, vb);
#pragma unroll
            for (int i = 0; i < 4; ++i) kv2[i] = ldnt(kb + (i * 8 + l8) * 4);
#pragma unroll
            for (int i = 0; i < 4; ++i) vv2[i] = ldnt(vb + (i * 8 + l8) * 4);
        }
        compute(kv, vv, t, false);
#pragma unroll
        for (int i = 0; i < 4; ++i) { kv[i] = kv2[i]; vv[i] = vv2[i]; }
    }
    if (tail) {
        const float *kb, *vb;
        mkaddr(nt, kb, vb);
#pragma unroll
        for (int i = 0; i < 4; ++i) kv[i] = ldnt(kb + (i * 8 + l8) * 4);
#pragma unroll
        for (int i = 0; i < 4; ++i) vv[i] = ldnt(vb + (i * 8 + l8) * 4);
        compute(kv, vv, nt, true);
    }

    // cross-group reductions (bits 3..5), once at the end
#pragma unroll
    for (int h = 0; h < GQA; ++h) {
        l_run[h] += __shfl_xor(l_run[h], 8);
        l_run[h] += __shfl_xor(l_run[h], 16);
        l_run[h] += __shfl_xor(l_run[h], 32);
#pragma unroll
        for (int i = 0; i < 4; ++i) {
            acc[h][i].x += __shfl_xor(acc[h][i].x, 8);
            acc[h][i].x += __shfl_xor(acc[h][i].x, 16);
            acc[h][i].x += __shfl_xor(acc[h][i].x, 32);
            acc[h][i].y += __shfl_xor(acc[h][i].y, 8);
            acc[h][i].y += __shfl_xor(acc[h][i].y, 16);
            acc[h][i].y += __shfl_xor(acc[h][i].y, 32);
            acc[h][i].z += __shfl_xor(acc[h][i].z, 8);
            acc[h][i].z += __shfl_xor(acc[h][i].z, 16);
            acc[h][i].z += __shfl_xor(acc[h][i].z, 32);
            acc[h][i].w += __shfl_xor(acc[h][i].w, 8);
            acc[h][i].w += __shfl_xor(acc[h][i].w, 16);
            acc[h][i].w += __shfl_xor(acc[h][i].w, 32);
        }
    }

    if (grp == 0) {
#pragma unroll
        for (int h = 0; h < GQA; ++h) {
#pragma unroll
            for (int i = 0; i < 4; ++i)
                *(float4*)&acc_lds[wave][h][(i * 8 + l8) * 4] = acc[h][i];
            if (l8 == 0) { m_lds[wave][h] = m_run[h]; l_lds[wave][h] = l_run[h]; }
        }
    }
    __syncthreads();

    // combine the 4 waves' partial softmax states; 512 outputs, 2 per thread
    for (int o = tid; o < GQA * HD; o += 256) {
        const int h = o >> 7;
        const int d = o & (HD - 1);
        float mm = -1e30f;
#pragma unroll
        for (int w = 0; w < 4; ++w) mm = fmaxf(mm, m_lds[w][h]);
        float num = 0.f, den = 0.f;
#pragma unroll
        for (int w = 0; w < 4; ++w) {
            const float wt = __expf(m_lds[w][h] - mm);
            num += wt * acc_lds[w][h][d];
            den += wt * l_lds[w][h];
        }
        out[(size_t)b * NH * HD + (g * GQA + h) * HD + d] = num / den;
    }
}

extern "C" void kernel_launch(void* const* d_in, const int* in_sizes, int n_in,
                              void* d_out, int out_size, void* d_ws, size_t ws_size,
                              hipStream_t stream) {
    const float* q    = (const float*)d_in[0];
    const float* k    = (const float*)d_in[1];
    const float* v    = (const float*)d_in[2];
    const float* kc   = (const float*)d_in[3];
    const float* vc   = (const float*)d_in[4];
    const void*  slot = d_in[5];
    const void*  bt   = d_in[6];
    const void*  cl   = d_in[7];
    float* out = (float*)d_out;

    dim3 grid(NKV, BATCH);
    pa_decode<<<grid, 256, 0, stream>>>(q, k, v, kc, vc, slot, bt, cl, out);
}